// Round 1
// baseline (5398.703 us; speedup 1.0000x reference)
//
#include <hip/hip_runtime.h>

#define EPS 1e-7f

constexpr int B = 8, C = 64, H = 256, W = 448;
constexpr int N = H * W;          // 114688
constexpr int P = B * N;          // 917504 source pixels

__global__ __launch_bounds__(256) void softsplat_scatter(
    const float* __restrict__ x,
    const float* __restrict__ flow,
    const float* __restrict__ metric,
    float* __restrict__ out,      // [B, C, N] numerator accumulator (pre-zeroed)
    float* __restrict__ den)      // [B, N]    denominator accumulator (pre-zeroed)
{
    int t = blockIdx.x * blockDim.x + threadIdx.x;
    if (t >= P) return;
    int b = t / N;
    int p = t - b * N;
    int h = p / W;
    int w = p - h * W;

    float fdx = flow[(size_t)(b * 2 + 0) * N + p];
    float fdy = flow[(size_t)(b * 2 + 1) * N + p];
    float m   = __expf(metric[(size_t)b * N + p]);

    float tx = (float)w + fdx;
    float ty = (float)h + fdy;
    float x0f = floorf(tx), y0f = floorf(ty);
    int x0 = (int)x0f, y0 = (int)y0f;
    int x1 = x0 + 1,   y1 = y0 + 1;
    float fx = tx - x0f, fy = ty - y0f;

    float w00 = (1.f - fx) * (1.f - fy);
    float w10 = fx * (1.f - fy);
    float w01 = (1.f - fx) * fy;
    float w11 = fx * fy;

    bool vx0 = (x0 >= 0) && (x0 < W);
    bool vx1 = (x1 >= 0) && (x1 < W);
    bool vy0 = (y0 >= 0) && (y0 < H);
    bool vy1 = (y1 >= 0) && (y1 < H);

    // clip indices (weight is zeroed when invalid, so add contributes 0 — matches ref)
    int cx0 = min(max(x0, 0), W - 1);
    int cx1 = min(max(x1, 0), W - 1);
    int cy0 = min(max(y0, 0), H - 1);
    int cy1 = min(max(y1, 0), H - 1);

    int i00 = cy0 * W + cx0;
    int i10 = cy0 * W + cx1;
    int i01 = cy1 * W + cx0;
    int i11 = cy1 * W + cx1;

    w00 = (vx0 && vy0) ? w00 : 0.f;
    w10 = (vx1 && vy0) ? w10 : 0.f;
    w01 = (vx0 && vy1) ? w01 : 0.f;
    w11 = (vx1 && vy1) ? w11 : 0.f;

    // denominator splat
    float* denb = den + (size_t)b * N;
    atomicAdd(denb + i00, m * w00);
    atomicAdd(denb + i10, m * w10);
    atomicAdd(denb + i01, m * w01);
    atomicAdd(denb + i11, m * w11);

    // numerator splat: all 64 channels
    const float* xb = x + (size_t)b * C * N + p;
    float* ob = out + (size_t)b * C * N;
    #pragma unroll 4
    for (int c = 0; c < C; ++c) {
        float v = xb[(size_t)c * N] * m;
        float* o = ob + (size_t)c * N;
        atomicAdd(o + i00, v * w00);
        atomicAdd(o + i10, v * w10);
        atomicAdd(o + i01, v * w01);
        atomicAdd(o + i11, v * w11);
    }
}

__global__ __launch_bounds__(256) void softsplat_norm(
    float* __restrict__ out, const float* __restrict__ den)
{
    size_t t = (size_t)blockIdx.x * blockDim.x + threadIdx.x;  // one float4
    size_t e = t * 4;
    if (e >= (size_t)B * C * N) return;
    size_t b = e / ((size_t)C * N);
    size_t p = (e - b * (size_t)C * N) % N;   // same c within the float4 (N % 4 == 0)

    float4 o = *reinterpret_cast<float4*>(out + e);
    const float4 d = *reinterpret_cast<const float4*>(den + b * N + p);
    o.x = o.x / (d.x + EPS);
    o.y = o.y / (d.y + EPS);
    o.z = o.z / (d.z + EPS);
    o.w = o.w / (d.w + EPS);
    *reinterpret_cast<float4*>(out + e) = o;
}

extern "C" void kernel_launch(void* const* d_in, const int* in_sizes, int n_in,
                              void* d_out, int out_size, void* d_ws, size_t ws_size,
                              hipStream_t stream) {
    const float* x      = (const float*)d_in[0];
    const float* flow   = (const float*)d_in[1];
    const float* metric = (const float*)d_in[2];
    float* out = (float*)d_out;
    float* den = (float*)d_ws;

    // zero accumulators (harness poisons with 0xAA and does not re-poison between replays)
    hipMemsetAsync(out, 0, (size_t)out_size * sizeof(float), stream);
    hipMemsetAsync(den, 0, (size_t)B * N * sizeof(float), stream);

    softsplat_scatter<<<(P + 255) / 256, 256, 0, stream>>>(x, flow, metric, out, den);

    size_t nvec4 = (size_t)B * C * N / 4;
    softsplat_norm<<<(int)((nvec4 + 255) / 256), 256, 0, stream>>>(out, den);
}

// Round 2
// 1315.758 us; speedup vs baseline: 4.1031x; 4.1031x over previous
//
#include <hip/hip_runtime.h>

#define EPS 1e-7f

constexpr int B = 8, C = 64, H = 256, W = 448;
constexpr int N = H * W;          // 114688
constexpr int P = B * N;          // 917504 source pixels

constexpr int TH = 32, TW = 64;   // exclusive output tile
constexpr int R  = 8;             // halo radius (covers |flow| <= 7)
constexpr int PS = TW + 4;        // padded LDS row stride (68: breaks 32-bank aliasing, keeps float4 align)
constexpr int PLANE = TH * PS;    // 2176 words
constexpr int NCH = 8;            // channels per chunk
constexpr int TILES_X = W / TW;   // 7
constexpr int TILES_Y = H / TH;   // 8
constexpr int TILES = B * TILES_X * TILES_Y;  // 448
constexpr int NTHREADS = 512;

__global__ __launch_bounds__(NTHREADS) void softsplat_gather(
    const float* __restrict__ x,
    const float* __restrict__ flow,
    const float* __restrict__ metric,
    float* __restrict__ out,      // [B, C, N] numerator
    float* __restrict__ den)      // [B, N]    denominator
{
    __shared__ float acc[NCH * PLANE];   // 69,632 B -> 2 blocks/CU

    const int tile  = blockIdx.x;
    const int chunk = blockIdx.y;        // 0..7 = channel chunks, 8 = denominator
    const int b  = tile / (TILES_X * TILES_Y);
    const int tp = tile % (TILES_X * TILES_Y);
    const int r0 = (tp / TILES_X) * TH;
    const int c0 = (tp % TILES_X) * TW;
    const int tid = threadIdx.x;
    const bool isden = (chunk == NCH);
    const int nplanes = isden ? 1 : NCH;

    for (int i = tid; i < nplanes * PLANE; i += NTHREADS) acc[i] = 0.f;
    __syncthreads();

    // halo source window, clipped to image
    const int hs0 = max(r0 - R, 0), hs1 = min(r0 + TH + R, H);
    const int ws0 = max(c0 - R, 0), ws1 = min(c0 + TW + R, W);
    const int HS = hs1 - hs0, WS = ws1 - ws0;
    const int nsrc = HS * WS;

    const float* fx_p = flow + (size_t)(b * 2 + 0) * N;
    const float* fy_p = flow + (size_t)(b * 2 + 1) * N;
    const float* m_p  = metric + (size_t)b * N;
    const float* xb   = x + ((size_t)b * C + (isden ? 0 : chunk * NCH)) * N;

    for (int s = tid; s < nsrc; s += NTHREADS) {
        const int sh = hs0 + s / WS;
        const int sw = ws0 + s % WS;
        const int sp = sh * W + sw;
        const float fdx = fx_p[sp], fdy = fy_p[sp];
        // outliers handled by the global-atomic fixup pass (exact complement predicate)
        if (fabsf(fdx) > (float)(R - 1) || fabsf(fdy) > (float)(R - 1)) continue;

        const float tx = (float)sw + fdx, ty = (float)sh + fdy;
        const float x0f = floorf(tx), y0f = floorf(ty);
        const int lx0 = (int)x0f - c0, ly0 = (int)y0f - r0;   // local corner coords
        const int lx1 = lx0 + 1,       ly1 = ly0 + 1;
        // tile membership == image validity (tile is interior to image)
        const bool vx0 = (unsigned)lx0 < (unsigned)TW;
        const bool vx1 = (unsigned)lx1 < (unsigned)TW;
        const bool vy0 = (unsigned)ly0 < (unsigned)TH;
        const bool vy1 = (unsigned)ly1 < (unsigned)TH;
        if (!((vx0 || vx1) && (vy0 || vy1))) continue;

        const float m = __expf(m_p[sp]);
        const float fxf = tx - x0f, fyf = ty - y0f;
        const float w00 = (vx0 && vy0) ? (1.f - fxf) * (1.f - fyf) * m : 0.f;
        const float w10 = (vx1 && vy0) ? fxf * (1.f - fyf) * m : 0.f;
        const float w01 = (vx0 && vy1) ? (1.f - fxf) * fyf * m : 0.f;
        const float w11 = (vx1 && vy1) ? fxf * fyf * m : 0.f;

        const int i00 = ly0 * PS + lx0;
        const int i10 = ly0 * PS + lx1;
        const int i01 = ly1 * PS + lx0;
        const int i11 = ly1 * PS + lx1;

        if (isden) {
            if (w00 != 0.f) atomicAdd(&acc[i00], w00);
            if (w10 != 0.f) atomicAdd(&acc[i10], w10);
            if (w01 != 0.f) atomicAdd(&acc[i01], w01);
            if (w11 != 0.f) atomicAdd(&acc[i11], w11);
        } else {
            #pragma unroll
            for (int c = 0; c < NCH; ++c) {
                const float v = xb[(size_t)c * N + sp];
                float* pl = acc + c * PLANE;
                if (w00 != 0.f) atomicAdd(pl + i00, v * w00);
                if (w10 != 0.f) atomicAdd(pl + i10, v * w10);
                if (w01 != 0.f) atomicAdd(pl + i01, v * w01);
                if (w11 != 0.f) atomicAdd(pl + i11, v * w11);
            }
        }
    }
    __syncthreads();

    // non-atomic coalesced writeback of the exclusive tile
    if (isden) {
        float* db = den + (size_t)b * N;
        for (int i = tid; i < TH * (TW / 4); i += NTHREADS) {
            const int yy = i / (TW / 4), xg = i % (TW / 4);
            const float* src = acc + yy * PS + xg * 4;
            *reinterpret_cast<float4*>(db + (size_t)(r0 + yy) * W + c0 + xg * 4) =
                make_float4(src[0], src[1], src[2], src[3]);
        }
    } else {
        for (int i = tid; i < NCH * TH * (TW / 4); i += NTHREADS) {
            const int c  = i / (TH * (TW / 4));
            const int rem = i % (TH * (TW / 4));
            const int yy = rem / (TW / 4), xg = rem % (TW / 4);
            const float* src = acc + c * PLANE + yy * PS + xg * 4;
            *reinterpret_cast<float4*>(
                out + ((size_t)(b * C + chunk * NCH + c) * H + r0 + yy) * W + c0 + xg * 4) =
                make_float4(src[0], src[1], src[2], src[3]);
        }
    }
}

// Fixup for the (practically nonexistent) sources with |flow| > R-1:
// exact complement of the gather's skip predicate; global atomics on top.
__global__ __launch_bounds__(256) void softsplat_outlier(
    const float* __restrict__ x,
    const float* __restrict__ flow,
    const float* __restrict__ metric,
    float* __restrict__ out,
    float* __restrict__ den)
{
    int t = blockIdx.x * blockDim.x + threadIdx.x;
    if (t >= P) return;
    int b = t / N;
    int p = t - b * N;
    float fdx = flow[(size_t)(b * 2 + 0) * N + p];
    float fdy = flow[(size_t)(b * 2 + 1) * N + p];
    if (fabsf(fdx) <= (float)(R - 1) && fabsf(fdy) <= (float)(R - 1)) return;

    int h = p / W, w = p - h * W;
    float m = __expf(metric[(size_t)b * N + p]);
    float tx = (float)w + fdx, ty = (float)h + fdy;
    float x0f = floorf(tx), y0f = floorf(ty);
    int x0 = (int)x0f, y0 = (int)y0f, x1 = x0 + 1, y1 = y0 + 1;
    float fx = tx - x0f, fy = ty - y0f;
    float w00 = (1.f - fx) * (1.f - fy), w10 = fx * (1.f - fy);
    float w01 = (1.f - fx) * fy,         w11 = fx * fy;
    bool vx0 = (x0 >= 0) && (x0 < W), vx1 = (x1 >= 0) && (x1 < W);
    bool vy0 = (y0 >= 0) && (y0 < H), vy1 = (y1 >= 0) && (y1 < H);
    int cx0 = min(max(x0, 0), W - 1), cx1 = min(max(x1, 0), W - 1);
    int cy0 = min(max(y0, 0), H - 1), cy1 = min(max(y1, 0), H - 1);
    int i00 = cy0 * W + cx0, i10 = cy0 * W + cx1;
    int i01 = cy1 * W + cx0, i11 = cy1 * W + cx1;
    w00 = (vx0 && vy0) ? w00 * m : 0.f;
    w10 = (vx1 && vy0) ? w10 * m : 0.f;
    w01 = (vx0 && vy1) ? w01 * m : 0.f;
    w11 = (vx1 && vy1) ? w11 * m : 0.f;

    float* denb = den + (size_t)b * N;
    if (w00 != 0.f) atomicAdd(denb + i00, w00);
    if (w10 != 0.f) atomicAdd(denb + i10, w10);
    if (w01 != 0.f) atomicAdd(denb + i01, w01);
    if (w11 != 0.f) atomicAdd(denb + i11, w11);

    const float* xb = x + (size_t)b * C * N + p;
    float* ob = out + (size_t)b * C * N;
    for (int c = 0; c < C; ++c) {
        float v = xb[(size_t)c * N];
        float* o = ob + (size_t)c * N;
        if (w00 != 0.f) atomicAdd(o + i00, v * w00);
        if (w10 != 0.f) atomicAdd(o + i10, v * w10);
        if (w01 != 0.f) atomicAdd(o + i01, v * w01);
        if (w11 != 0.f) atomicAdd(o + i11, v * w11);
    }
}

__global__ __launch_bounds__(256) void softsplat_norm(
    float* __restrict__ out, const float* __restrict__ den)
{
    size_t t = (size_t)blockIdx.x * blockDim.x + threadIdx.x;  // one float4
    size_t e = t * 4;
    if (e >= (size_t)B * C * N) return;
    size_t b = e / ((size_t)C * N);
    size_t p = (e - b * (size_t)C * N) % N;   // N % 4 == 0

    float4 o = *reinterpret_cast<float4*>(out + e);
    const float4 d = *reinterpret_cast<const float4*>(den + b * N + p);
    o.x = o.x / (d.x + EPS);
    o.y = o.y / (d.y + EPS);
    o.z = o.z / (d.z + EPS);
    o.w = o.w / (d.w + EPS);
    *reinterpret_cast<float4*>(out + e) = o;
}

extern "C" void kernel_launch(void* const* d_in, const int* in_sizes, int n_in,
                              void* d_out, int out_size, void* d_ws, size_t ws_size,
                              hipStream_t stream) {
    const float* x      = (const float*)d_in[0];
    const float* flow   = (const float*)d_in[1];
    const float* metric = (const float*)d_in[2];
    float* out = (float*)d_out;
    float* den = (float*)d_ws;

    // No memsets needed: gather writes every element of out and den.
    dim3 grid(TILES, NCH + 1);  // 448 tiles x 9 chunks (8 channel chunks + 1 den)
    softsplat_gather<<<grid, NTHREADS, 0, stream>>>(x, flow, metric, out, den);

    softsplat_outlier<<<(P + 255) / 256, 256, 0, stream>>>(x, flow, metric, out, den);

    size_t nvec4 = (size_t)B * C * N / 4;
    softsplat_norm<<<(int)((nvec4 + 255) / 256), 256, 0, stream>>>(out, den);
}